// Round 1
// baseline (5382.889 us; speedup 1.0000x reference)
//
#include <hip/hip_runtime.h>
#include <math.h>

#define Bn   64
#define Sn   512
#define EMBn 128
#define HIDn 256
#define NG   1024   // 4*HID
#define NK   384    // 256 (U/h) + 128 (W/x)
#define NTAG 9

typedef short v8s __attribute__((ext_vector_type(8)));
typedef float v4f __attribute__((ext_vector_type(4)));

__device__ inline unsigned short f2bf(float f){
  union { float f; unsigned u; } v; v.f = f;
  unsigned r = v.u + 0x7FFFu + ((v.u >> 16) & 1u);
  return (unsigned short)(r >> 16);
}
__device__ inline float bf2f(unsigned short h){
  union { unsigned u; float f; } v; v.u = ((unsigned)h) << 16;
  return v.f;
}
__device__ inline float sigm(float x){ return 1.0f/(1.0f + __expf(-x)); }
__device__ inline float tanh_(float x){
  x = fminf(fmaxf(x, -15.0f), 15.0f);
  float e = __expf(2.0f*x);
  return (e - 1.0f)/(e + 1.0f);
}

// ---------------------------------------------------------------------------
// Pack U (256x1024) and W (128x1024) into UW_pk[d][col'][k], bf16, where
// col' = unit*4 + gate (gate order i,f,g,o), k<256 from U, k>=256 from W.
// Also pack bias b_pk[d][col'].
// ---------------------------------------------------------------------------
__global__ void k_conv(const float* __restrict__ Wf, const float* __restrict__ Uf,
                       const float* __restrict__ bf_, const float* __restrict__ Wb,
                       const float* __restrict__ Ub, const float* __restrict__ bb_,
                       unsigned short* __restrict__ UW, float* __restrict__ bpk)
{
  int col = blockIdx.x;        // 0..1023
  int d   = blockIdx.y;        // 0..1
  const float* U = d ? Ub : Uf;
  const float* W = d ? Wb : Wf;
  const float* bias = d ? bb_ : bf_;
  int j = col >> 2, g = col & 3, c = g*HIDn + j;
  unsigned short* dst = UW + ((size_t)d*NG + col)*NK;
  for (int k = threadIdx.x; k < NK; k += 128){
    float v = (k < HIDn) ? U[(size_t)k*NG + c] : W[(size_t)(k - HIDn)*NG + c];
    dst[k] = f2bf(v);
  }
  if (threadIdx.x == 0) bpk[d*NG + col] = bias[c];
}

// ---------------------------------------------------------------------------
// text_lens: count nonzero tokens per batch row. Write float to d_out, int to ws.
// ---------------------------------------------------------------------------
__global__ void k_lens(const int* __restrict__ text, float* __restrict__ out_lens,
                       int* __restrict__ lens_i)
{
  int b = blockIdx.x, lane = threadIdx.x;
  int cnt = 0;
  for (int s = lane; s < Sn; s += 64) cnt += (text[b*Sn + s] != 0) ? 1 : 0;
  for (int off = 32; off; off >>= 1) cnt += __shfl_down(cnt, off);
  if (lane == 0){ lens_i[b] = cnt; out_lens[b] = (float)cnt; }
}

// ---------------------------------------------------------------------------
// One LSTM time step, both directions. grid = (8 colgroups, 4 batchgroups, 2 dirs),
// block = 256. Block owns 16 batches x 32 hidden units (128 packed cols).
// z[b][col'] = h_prev@U + x@W + bias via mfma_f32_16x16x32_bf16, then gates.
// h written to h_hist[d][t_act][b][j] (bf16), c kept in c_state (f32).
// ---------------------------------------------------------------------------
__global__ __launch_bounds__(256) void k_step(
    const int* __restrict__ text, const float* __restrict__ emb,
    const unsigned short* __restrict__ UW, const float* __restrict__ bpk,
    unsigned short* __restrict__ h_hist, float* __restrict__ c_state, int t)
{
  __shared__ unsigned short A_s[16][392];   // [m][k], k<256 = h, 256..383 = x, +8 pad
  __shared__ float z_s[16][132];            // [m][local col']
  int cg = blockIdx.x, bg = blockIdx.y, d = blockIdx.z;
  int tid = threadIdx.x;
  int t_act = d ? (Sn - 1 - t) : t;

  // stage x (emb gather, fp32 -> bf16) into A_s[:, 256..384)
  for (int idx = tid; idx < 16*EMBn; idx += 256){
    int m = idx >> 7, e = idx & 127;
    int b = bg*16 + m;
    int tok = text[b*Sn + t_act];
    A_s[m][HIDn + e] = f2bf(emb[(size_t)tok*EMBn + e]);
  }
  // stage h_prev into A_s[:, 0..256)
  if (t > 0){
    int tp = d ? (t_act + 1) : (t_act - 1);
    const unsigned short* hsrc = h_hist + ((size_t)(d*Sn + tp)*Bn)*HIDn;
    for (int idx = tid; idx < 16*64; idx += 256){
      int m = idx >> 6, j4 = (idx & 63)*4;
      int b = bg*16 + m;
      ushort4 v = *(const ushort4*)(hsrc + (size_t)b*HIDn + j4);
      *(ushort4*)&A_s[m][j4] = v;
    }
  }
  __syncthreads();

  // MFMA: 4 waves, wave wv handles local cols [wv*32, wv*32+32)
  int wv = tid >> 6, lane = tid & 63, q = lane >> 4, r = lane & 15;
  v4f acc0 = {0.f,0.f,0.f,0.f}, acc1 = {0.f,0.f,0.f,0.f};
  const unsigned short* Bbase = UW + ((size_t)d*NG + cg*128 + wv*32 + r)*NK;
  int kt0 = (t == 0) ? 8 : 0;   // t==0: h_prev==0, skip U part (k tiles 0..7)
  for (int kt = kt0; kt < 12; ++kt){
    int ko = kt*32 + q*8;
    v8s a  = *(const v8s*)&A_s[r][ko];
    v8s b0 = *(const v8s*)(Bbase + ko);
    v8s b1 = *(const v8s*)(Bbase + (size_t)16*NK + ko);
    acc0 = __builtin_amdgcn_mfma_f32_16x16x32_bf16(a, b0, acc0, 0, 0, 0);
    acc1 = __builtin_amdgcn_mfma_f32_16x16x32_bf16(a, b1, acc1, 0, 0, 0);
  }
  #pragma unroll
  for (int i = 0; i < 4; ++i){
    z_s[q*4 + i][wv*32 + r]      = acc0[i];   // row = m (C/D: row=quad*4+reg, col=lane&15)
    z_s[q*4 + i][wv*32 + 16 + r] = acc1[i];
  }
  __syncthreads();

  // elementwise: thread -> (m = tid>>4, unit-pair up = tid&15)
  {
    int m = tid >> 4, up = tid & 15;
    int lc = up*8;                       // 8 packed cols = 2 units x 4 gates
    int b  = bg*16 + m;
    int u0 = cg*32 + up*2;
    const float* bp = bpk + d*NG + cg*128 + lc;
    float z[8];
    #pragma unroll
    for (int i = 0; i < 8; ++i) z[i] = z_s[m][lc + i] + bp[i];
    float cp0 = 0.f, cp1 = 0.f;
    if (t > 0){
      const float* cp = c_state + ((size_t)d*Bn + b)*HIDn + u0;
      cp0 = cp[0]; cp1 = cp[1];
    }
    float i0 = sigm(z[0]), f0 = sigm(z[1]), g0 = tanh_(z[2]), o0 = sigm(z[3]);
    float i1 = sigm(z[4]), f1 = sigm(z[5]), g1 = tanh_(z[6]), o1 = sigm(z[7]);
    float c0 = f0*cp0 + i0*g0, c1 = f1*cp1 + i1*g1;
    float h0 = o0*tanh_(c0),  h1 = o1*tanh_(c1);
    float* cw = c_state + ((size_t)d*Bn + b)*HIDn + u0;
    cw[0] = c0; cw[1] = c1;
    unsigned short* hw = h_hist + ((size_t)(d*Sn + t_act)*Bn + b)*HIDn + u0;
    hw[0] = f2bf(h0); hw[1] = f2bf(h1);
  }
}

// ---------------------------------------------------------------------------
// logits[b][s][tag] = concat(hf,hb) @ W_d + b_d   (one thread per output elem)
// ---------------------------------------------------------------------------
__global__ __launch_bounds__(256) void k_logits(
    const unsigned short* __restrict__ h_hist, const float* __restrict__ Wd,
    const float* __restrict__ bd, float* __restrict__ out)
{
  int n = blockIdx.x*256 + threadIdx.x;
  if (n >= Bn*Sn*NTAG) return;
  int tag = n % NTAG;
  int tok = n / NTAG;              // b*512 + s
  int b = tok >> 9, s = tok & 511;
  const unsigned short* hf = h_hist + ((size_t)(0*Sn + s)*Bn + b)*HIDn;
  const unsigned short* hb = h_hist + ((size_t)(1*Sn + s)*Bn + b)*HIDn;
  float acc = bd[tag];
  for (int j = 0; j < HIDn; ++j) acc += bf2f(hf[j]) * Wd[j*NTAG + tag];
  for (int j = 0; j < HIDn; ++j) acc += bf2f(hb[j]) * Wd[(HIDn + j)*NTAG + tag];
  out[n] = acc;
}

// ---------------------------------------------------------------------------
// CRF: sequence score (parallel over s) + log-norm (9-lane logsumexp scan).
// One block (1 wave) per batch element.
// ---------------------------------------------------------------------------
__global__ __launch_bounds__(64) void k_crf(
    const float* __restrict__ logits, const int* __restrict__ labels,
    const float* __restrict__ trans, const int* __restrict__ lens_i,
    float* __restrict__ out_ll)
{
  int b = blockIdx.x, lane = threadIdx.x;
  int len = lens_i[b];
  const float* lg = logits + (size_t)b*Sn*NTAG;
  const int* lab = labels + b*Sn;

  float sc = 0.f;
  for (int s = lane; s < Sn; s += 64){
    if (s < len)     sc += lg[s*NTAG + lab[s]];
    if (s < len - 1) sc += trans[lab[s]*NTAG + lab[s+1]];
  }
  for (int off = 32; off; off >>= 1) sc += __shfl_down(sc, off);
  sc = __shfl(sc, 0);

  int j = (lane < NTAG) ? lane : (NTAG - 1);
  float Tj[NTAG];
  #pragma unroll
  for (int i = 0; i < NTAG; ++i) Tj[i] = trans[i*NTAG + j];
  float alpha = lg[j];
  float nxt = lg[NTAG + j];
  for (int t = 1; t < Sn; ++t){
    float cur = nxt;
    if (t < Sn - 1) nxt = lg[(t+1)*NTAG + j];
    float v[NTAG]; float m;
    v[0] = __shfl(alpha, 0) + Tj[0]; m = v[0];
    #pragma unroll
    for (int i = 1; i < NTAG; ++i){ v[i] = __shfl(alpha, i) + Tj[i]; m = fmaxf(m, v[i]); }
    float ssum = 0.f;
    #pragma unroll
    for (int i = 0; i < NTAG; ++i) ssum += __expf(v[i] - m);
    float na = m + __logf(ssum) + cur;
    if (t < len) alpha = na;
  }
  float m2 = __shfl(alpha, 0);
  #pragma unroll
  for (int i = 1; i < NTAG; ++i) m2 = fmaxf(m2, __shfl(alpha, i));
  float s2 = 0.f;
  #pragma unroll
  for (int i = 0; i < NTAG; ++i) s2 += __expf(__shfl(alpha, i) - m2);
  float ln = m2 + __logf(s2);
  if (lane == 0) out_ll[b] = sc - ln;
}

// ---------------------------------------------------------------------------
extern "C" void kernel_launch(void* const* d_in, const int* in_sizes, int n_in,
                              void* d_out, int out_size, void* d_ws, size_t ws_size,
                              hipStream_t stream)
{
  const int*   text   = (const int*)  d_in[0];
  const int*   labels = (const int*)  d_in[1];
  const float* emb    = (const float*)d_in[2];
  const float* W_f    = (const float*)d_in[3];
  const float* U_f    = (const float*)d_in[4];
  const float* b_f    = (const float*)d_in[5];
  const float* W_b    = (const float*)d_in[6];
  const float* U_b    = (const float*)d_in[7];
  const float* b_b    = (const float*)d_in[8];
  const float* W_d    = (const float*)d_in[9];
  const float* b_d    = (const float*)d_in[10];
  const float* trans  = (const float*)d_in[11];
  float* out = (float*)d_out;                  // [logits 294912][lens 64][ll 64]

  char* w = (char*)d_ws;
  int*            lens_i  = (int*)w;                                    //     256 B
  unsigned short* UW      = (unsigned short*)(w + 256);                 // 1572864 B
  float*          bpk     = (float*)(w + 256 + 1572864);                //    8192 B
  float*          c_state = (float*)(w + 256 + 1572864 + 8192);         //  131072 B
  unsigned short* h_hist  = (unsigned short*)(w + 1712384);             //  32 MiB

  hipLaunchKernelGGL(k_conv, dim3(NG, 2), dim3(128), 0, stream,
                     W_f, U_f, b_f, W_b, U_b, b_b, UW, bpk);
  hipLaunchKernelGGL(k_lens, dim3(Bn), dim3(64), 0, stream,
                     text, out + Bn*Sn*NTAG, lens_i);
  for (int t = 0; t < Sn; ++t){
    hipLaunchKernelGGL(k_step, dim3(8, 4, 2), dim3(256), 0, stream,
                       text, emb, UW, bpk, h_hist, c_state, t);
  }
  hipLaunchKernelGGL(k_logits, dim3((Bn*Sn*NTAG + 255)/256), dim3(256), 0, stream,
                     h_hist, W_d, b_d, out);
  hipLaunchKernelGGL(k_crf, dim3(Bn), dim3(64), 0, stream,
                     out, labels, trans, lens_i, out + Bn*Sn*NTAG + Bn);
}

// Round 2
// 4883.305 us; speedup vs baseline: 1.1023x; 1.1023x over previous
//
#include <hip/hip_runtime.h>
#include <math.h>

#define Bn   64
#define Sn   512
#define EMBn 128
#define HIDn 256
#define NG   1024   // 4*HID
#define NK   384    // 256 (U/h) + 128 (W/x)
#define NTAG 9

typedef short v8s __attribute__((ext_vector_type(8)));
typedef float v4f __attribute__((ext_vector_type(4)));

__device__ inline unsigned short f2bf(float f){
  union { float f; unsigned u; } v; v.f = f;
  unsigned r = v.u + 0x7FFFu + ((v.u >> 16) & 1u);
  return (unsigned short)(r >> 16);
}
__device__ inline float bf2f(unsigned short h){
  union { unsigned u; float f; } v; v.u = ((unsigned)h) << 16;
  return v.f;
}
__device__ inline float sigm(float x){ return 1.0f/(1.0f + __expf(-x)); }
__device__ inline float tanh_(float x){
  x = fminf(fmaxf(x, -15.0f), 15.0f);
  float e = __expf(2.0f*x);
  return (e - 1.0f)/(e + 1.0f);
}

// ---------------------------------------------------------------------------
// Zero the sync flags (ws is poisoned 0xAA before every call).
// ---------------------------------------------------------------------------
__global__ void k_zero(int* __restrict__ p, int n){
  int i = blockIdx.x*256 + threadIdx.x;
  if (i < n) p[i] = 0;
}

// ---------------------------------------------------------------------------
// Pack U (256x1024) and W (128x1024) into UW_pk[d][col'][k], bf16, where
// col' = unit*4 + gate (gate order i,f,g,o), k<256 from U, k>=256 from W.
// ---------------------------------------------------------------------------
__global__ void k_conv(const float* __restrict__ Wf, const float* __restrict__ Uf,
                       const float* __restrict__ bf_, const float* __restrict__ Wb,
                       const float* __restrict__ Ub, const float* __restrict__ bb_,
                       unsigned short* __restrict__ UW, float* __restrict__ bpk)
{
  int col = blockIdx.x;        // 0..1023
  int d   = blockIdx.y;        // 0..1
  const float* U = d ? Ub : Uf;
  const float* W = d ? Wb : Wf;
  const float* bias = d ? bb_ : bf_;
  int j = col >> 2, g = col & 3, c = g*HIDn + j;
  unsigned short* dst = UW + ((size_t)d*NG + col)*NK;
  for (int k = threadIdx.x; k < NK; k += 128){
    float v = (k < HIDn) ? U[(size_t)k*NG + c] : W[(size_t)(k - HIDn)*NG + c];
    dst[k] = f2bf(v);
  }
  if (threadIdx.x == 0) bpk[d*NG + col] = bias[c];
}

// ---------------------------------------------------------------------------
__global__ void k_lens(const int* __restrict__ text, float* __restrict__ out_lens,
                       int* __restrict__ lens_i)
{
  int b = blockIdx.x, lane = threadIdx.x;
  int cnt = 0;
  for (int s = lane; s < Sn; s += 64) cnt += (text[b*Sn + s] != 0) ? 1 : 0;
  for (int off = 32; off; off >>= 1) cnt += __shfl_down(cnt, off);
  if (lane == 0){ lens_i[b] = cnt; out_lens[b] = (float)cnt; }
}

// ---------------------------------------------------------------------------
// Persistent bidirectional LSTM. grid = (8 cg, 4 bg, 2 d), block = 256.
// Block owns 16 batches x 128 packed gate-cols. Weights register-stationary
// (2 col-tiles x 12 k-tiles of v8s per wave). c-state in registers.
// Per step: stage x (emb gather) + h_prev (agent atomics) -> MFMA -> gates ->
// h store (agent atomics) -> flag release-add; consumers spin acquire-load.
// ---------------------------------------------------------------------------
__global__ __launch_bounds__(256) void k_lstm(
    const int* __restrict__ text, const float* __restrict__ emb,
    const unsigned short* __restrict__ UW, const float* __restrict__ bpk,
    unsigned short* __restrict__ h_hist, int* __restrict__ flags)
{
  __shared__ unsigned short A_s[16][392];   // [m][k]: k<256 = h_prev, 256..383 = x
  __shared__ float z_s[16][132];            // [m][local col']
  int cg = blockIdx.x, bg = blockIdx.y, d = blockIdx.z;
  int tid = threadIdx.x;
  int wv = tid >> 6, lane = tid & 63, q = lane >> 4, r = lane & 15;
  int gidx = d*4 + bg;
  int* gflag = flags + gidx*Sn;

  // ---- load register-stationary weight fragments (once) ----
  v8s wf[2][12];
  {
    const unsigned short* base = UW + ((size_t)(d*NG + cg*128 + wv*32 + r))*NK;
    #pragma unroll
    for (int ct = 0; ct < 2; ++ct)
      #pragma unroll
      for (int kt = 0; kt < 12; ++kt)
        wf[ct][kt] = *(const v8s*)(base + (size_t)ct*16*NK + kt*32 + q*8);
  }
  // ---- per-thread elementwise assignment + bias + c-state in regs ----
  int m_e = tid >> 4, up_e = tid & 15;
  int b_e  = bg*16 + m_e;
  int u0_e = cg*32 + up_e*2;
  float bp_[8];
  #pragma unroll
  for (int i = 0; i < 8; ++i) bp_[i] = bpk[d*NG + cg*128 + up_e*8 + i];
  float c0 = 0.f, c1 = 0.f;

  for (int t = 0; t < Sn; ++t){
    int t_act = d ? (Sn - 1 - t) : t;

    // stage x (emb gather, fp32 -> bf16) into A_s[:, 256..384)
    for (int idx = tid; idx < 16*EMBn; idx += 256){
      int m = idx >> 7, e = idx & 127;
      int tok = text[(bg*16 + m)*Sn + t_act];
      A_s[m][HIDn + e] = f2bf(emb[(size_t)tok*EMBn + e]);
    }

    if (t > 0){
      // wait for all 8 cg blocks of this (bg,d) to publish h_{t-1}
      if (tid == 0){
        while (__hip_atomic_load(gflag + (t-1), __ATOMIC_ACQUIRE,
                                 __HIP_MEMORY_SCOPE_AGENT) < 8)
          __builtin_amdgcn_s_sleep(1);
      }
      __syncthreads();
      int tp = d ? (t_act + 1) : (t_act - 1);
      const unsigned long long* hsrc = (const unsigned long long*)
          (h_hist + ((size_t)(d*Sn + tp)*Bn)*HIDn);
      for (int idx = tid; idx < 16*64; idx += 256){
        int m = idx >> 6, j8 = idx & 63;
        unsigned long long v = __hip_atomic_load(
            hsrc + (size_t)(bg*16 + m)*(HIDn/4) + j8,
            __ATOMIC_RELAXED, __HIP_MEMORY_SCOPE_AGENT);
        *(unsigned long long*)&A_s[m][j8*4] = v;
      }
    } else {
      for (int idx = tid; idx < 16*64; idx += 256){
        int m = idx >> 6;
        *(unsigned long long*)&A_s[m][(idx & 63)*4] = 0ULL;
      }
    }
    __syncthreads();

    // ---- MFMA: z[16][128] = [h_prev | x] @ UW ----
    v4f acc0 = {0.f,0.f,0.f,0.f}, acc1 = {0.f,0.f,0.f,0.f};
    #pragma unroll
    for (int kt = 0; kt < 12; ++kt){
      v8s a = *(const v8s*)&A_s[r][kt*32 + q*8];
      acc0 = __builtin_amdgcn_mfma_f32_16x16x32_bf16(a, wf[0][kt], acc0, 0, 0, 0);
      acc1 = __builtin_amdgcn_mfma_f32_16x16x32_bf16(a, wf[1][kt], acc1, 0, 0, 0);
    }
    #pragma unroll
    for (int i = 0; i < 4; ++i){
      z_s[q*4 + i][wv*32 + r]      = acc0[i];   // C/D: row=quad*4+reg, col=lane&15
      z_s[q*4 + i][wv*32 + 16 + r] = acc1[i];
    }
    __syncthreads();

    // ---- gates + state update (c in registers) ----
    {
      float z[8];
      #pragma unroll
      for (int i = 0; i < 8; ++i) z[i] = z_s[m_e][up_e*8 + i] + bp_[i];
      float i0 = sigm(z[0]), f0 = sigm(z[1]), g0 = tanh_(z[2]), o0 = sigm(z[3]);
      float i1 = sigm(z[4]), f1 = sigm(z[5]), g1 = tanh_(z[6]), o1 = sigm(z[7]);
      c0 = f0*c0 + i0*g0;
      c1 = f1*c1 + i1*g1;
      float h0 = o0*tanh_(c0), h1 = o1*tanh_(c1);
      unsigned int hv = (unsigned int)f2bf(h0) | ((unsigned int)f2bf(h1) << 16);
      unsigned int* hw = (unsigned int*)
          (h_hist + ((size_t)(d*Sn + t_act)*Bn + b_e)*HIDn + u0_e);
      __hip_atomic_store(hw, hv, __ATOMIC_RELAXED, __HIP_MEMORY_SCOPE_AGENT);
    }
    __threadfence();
    __syncthreads();
    if (tid == 0)
      __hip_atomic_fetch_add(gflag + t, 1, __ATOMIC_RELEASE,
                             __HIP_MEMORY_SCOPE_AGENT);
  }
}

// ---------------------------------------------------------------------------
// logits[b][s][tag] = concat(hf,hb) @ W_d + b_d.  One thread per token,
// W_d broadcast from LDS, h loaded as uint4 (8 bf16 / 16B).
// ---------------------------------------------------------------------------
__global__ __launch_bounds__(256) void k_logits(
    const unsigned short* __restrict__ h_hist, const float* __restrict__ Wd,
    const float* __restrict__ bd, float* __restrict__ out)
{
  __shared__ float Wd_s[2*HIDn*NTAG];   // 4608 floats
  __shared__ float bd_s[NTAG];
  for (int i = threadIdx.x; i < 2*HIDn*NTAG; i += 256) Wd_s[i] = Wd[i];
  if (threadIdx.x < NTAG) bd_s[threadIdx.x] = bd[threadIdx.x];
  __syncthreads();

  int n = blockIdx.x*256 + threadIdx.x;   // n = b*512 + s, n < 32768
  int b = n >> 9, s = n & 511;
  float acc[NTAG];
  #pragma unroll
  for (int k = 0; k < NTAG; ++k) acc[k] = bd_s[k];

  const uint4* hf = (const uint4*)(h_hist + ((size_t)s*Bn + b)*HIDn);
  const uint4* hb = (const uint4*)(h_hist + ((size_t)(Sn + s)*Bn + b)*HIDn);
  #pragma unroll 4
  for (int ch = 0; ch < HIDn/8; ++ch){
    uint4 vf = hf[ch], vb = hb[ch];
    unsigned int wsv[8] = {vf.x, vf.y, vf.z, vf.w, vb.x, vb.y, vb.z, vb.w};
    #pragma unroll
    for (int half = 0; half < 2; ++half){
      int jbase = half*HIDn + ch*8;
      #pragma unroll
      for (int e = 0; e < 4; ++e){
        unsigned int u = wsv[half*4 + e];
        float hlo = bf2f((unsigned short)(u & 0xFFFF));
        float hhi = bf2f((unsigned short)(u >> 16));
        const float* w0 = &Wd_s[(jbase + e*2    )*NTAG];
        const float* w1 = &Wd_s[(jbase + e*2 + 1)*NTAG];
        #pragma unroll
        for (int k = 0; k < NTAG; ++k) acc[k] += hlo*w0[k] + hhi*w1[k];
      }
    }
  }
  float* o = out + (size_t)n*NTAG;
  #pragma unroll
  for (int k = 0; k < NTAG; ++k) o[k] = acc[k];
}

// ---------------------------------------------------------------------------
// CRF: sequence score + log-norm scan. One wave per batch element.
// ---------------------------------------------------------------------------
__global__ __launch_bounds__(64) void k_crf(
    const float* __restrict__ logits, const int* __restrict__ labels,
    const float* __restrict__ trans, const int* __restrict__ lens_i,
    float* __restrict__ out_ll)
{
  int b = blockIdx.x, lane = threadIdx.x;
  int len = lens_i[b];
  const float* lg = logits + (size_t)b*Sn*NTAG;
  const int* lab = labels + b*Sn;

  float sc = 0.f;
  for (int s = lane; s < Sn; s += 64){
    if (s < len)     sc += lg[s*NTAG + lab[s]];
    if (s < len - 1) sc += trans[lab[s]*NTAG + lab[s+1]];
  }
  for (int off = 32; off; off >>= 1) sc += __shfl_down(sc, off);
  sc = __shfl(sc, 0);

  int j = (lane < NTAG) ? lane : (NTAG - 1);
  float Tj[NTAG];
  #pragma unroll
  for (int i = 0; i < NTAG; ++i) Tj[i] = trans[i*NTAG + j];
  float alpha = lg[j];
  float nxt = lg[NTAG + j];
  for (int t = 1; t < Sn; ++t){
    float cur = nxt;
    if (t < Sn - 1) nxt = lg[(t+1)*NTAG + j];
    float v[NTAG]; float m;
    v[0] = __shfl(alpha, 0) + Tj[0]; m = v[0];
    #pragma unroll
    for (int i = 1; i < NTAG; ++i){ v[i] = __shfl(alpha, i) + Tj[i]; m = fmaxf(m, v[i]); }
    float ssum = 0.f;
    #pragma unroll
    for (int i = 0; i < NTAG; ++i) ssum += __expf(v[i] - m);
    float na = m + __logf(ssum) + cur;
    if (t < len) alpha = na;
  }
  float m2 = __shfl(alpha, 0);
  #pragma unroll
  for (int i = 1; i < NTAG; ++i) m2 = fmaxf(m2, __shfl(alpha, i));
  float s2 = 0.f;
  #pragma unroll
  for (int i = 0; i < NTAG; ++i) s2 += __expf(__shfl(alpha, i) - m2);
  float ln = m2 + __logf(s2);
  if (lane == 0) out_ll[b] = sc - ln;
}

// ---------------------------------------------------------------------------
extern "C" void kernel_launch(void* const* d_in, const int* in_sizes, int n_in,
                              void* d_out, int out_size, void* d_ws, size_t ws_size,
                              hipStream_t stream)
{
  const int*   text   = (const int*)  d_in[0];
  const int*   labels = (const int*)  d_in[1];
  const float* emb    = (const float*)d_in[2];
  const float* W_f    = (const float*)d_in[3];
  const float* U_f    = (const float*)d_in[4];
  const float* b_f    = (const float*)d_in[5];
  const float* W_b    = (const float*)d_in[6];
  const float* U_b    = (const float*)d_in[7];
  const float* b_b    = (const float*)d_in[8];
  const float* W_d    = (const float*)d_in[9];
  const float* b_d    = (const float*)d_in[10];
  const float* trans  = (const float*)d_in[11];
  float* out = (float*)d_out;                  // [logits 294912][lens 64][ll 64]

  char* w = (char*)d_ws;
  int*            lens_i  = (int*)w;                         //     256 B
  int*            flags   = (int*)(w + 256);                 //   16384 B (8 groups x 512)
  unsigned short* UW      = (unsigned short*)(w + 16640);    // 1572864 B
  float*          bpk     = (float*)(w + 16640 + 1572864);   //    8192 B
  unsigned short* h_hist  = (unsigned short*)(w + 1597696);  //  32 MiB

  hipLaunchKernelGGL(k_zero, dim3(16), dim3(256), 0, stream, flags, 8*Sn);
  hipLaunchKernelGGL(k_conv, dim3(NG, 2), dim3(128), 0, stream,
                     W_f, U_f, b_f, W_b, U_b, b_b, UW, bpk);
  hipLaunchKernelGGL(k_lens, dim3(Bn), dim3(64), 0, stream,
                     text, out + Bn*Sn*NTAG, lens_i);

  void* args[] = { (void*)&text, (void*)&emb, (void*)&UW, (void*)&bpk,
                   (void*)&h_hist, (void*)&flags };
  hipLaunchCooperativeKernel((const void*)k_lstm, dim3(8, 4, 2), dim3(256),
                             args, 0, stream);

  hipLaunchKernelGGL(k_logits, dim3(Bn*Sn/256), dim3(256), 0, stream,
                     h_hist, W_d, b_d, out);
  hipLaunchKernelGGL(k_crf, dim3(Bn), dim3(64), 0, stream,
                     out, labels, trans, lens_i, out + Bn*Sn*NTAG + Bn);
}

// Round 3
// 2708.270 us; speedup vs baseline: 1.9876x; 1.8031x over previous
//
#include <hip/hip_runtime.h>
#include <math.h>

#define Bn   64
#define Sn   512
#define EMBn 128
#define HIDn 256
#define NG   1024   // 4*HID
#define NK   384    // 256 (U/h) + 128 (W/x)
#define NTAG 9

typedef short v8s __attribute__((ext_vector_type(8)));
typedef float v4f __attribute__((ext_vector_type(4)));
typedef unsigned long long u64t;

__device__ inline unsigned short f2bf(float f){
  union { float f; unsigned u; } v; v.f = f;
  unsigned r = v.u + 0x7FFFu + ((v.u >> 16) & 1u);
  return (unsigned short)(r >> 16);
}
__device__ inline float bf2f(unsigned short h){
  union { unsigned u; float f; } v; v.u = ((unsigned)h) << 16;
  return v.f;
}
__device__ inline float sigm(float x){ return 1.0f/(1.0f + __expf(-x)); }
__device__ inline float tanh_(float x){
  x = fminf(fmaxf(x, -15.0f), 15.0f);
  float e = __expf(2.0f*x);
  return (e - 1.0f)/(e + 1.0f);
}

// ---------------------------------------------------------------------------
__global__ void k_zero(int* __restrict__ p, int n){
  int i = blockIdx.x*64 + threadIdx.x;
  if (i < n) p[i] = 0;
}

// ---------------------------------------------------------------------------
// Pack U (256x1024) and W (128x1024) into UW[d][col'][k] bf16; col'=unit*4+gate.
// ---------------------------------------------------------------------------
__global__ void k_conv(const float* __restrict__ Wf, const float* __restrict__ Uf,
                       const float* __restrict__ bf_, const float* __restrict__ Wb,
                       const float* __restrict__ Ub, const float* __restrict__ bb_,
                       unsigned short* __restrict__ UW, float* __restrict__ bpk)
{
  int col = blockIdx.x;        // 0..1023
  int d   = blockIdx.y;        // 0..1
  const float* U = d ? Ub : Uf;
  const float* W = d ? Wb : Wf;
  const float* bias = d ? bb_ : bf_;
  int j = col >> 2, g = col & 3, c = g*HIDn + j;
  unsigned short* dst = UW + ((size_t)d*NG + col)*NK;
  for (int k = threadIdx.x; k < NK; k += 128){
    float v = (k < HIDn) ? U[(size_t)k*NG + c] : W[(size_t)(k - HIDn)*NG + c];
    dst[k] = f2bf(v);
  }
  if (threadIdx.x == 0) bpk[d*NG + col] = bias[c];
}

// ---------------------------------------------------------------------------
__global__ void k_lens(const int* __restrict__ text, float* __restrict__ out_lens,
                       int* __restrict__ lens_i)
{
  int b = blockIdx.x, lane = threadIdx.x;
  int cnt = 0;
  for (int s = lane; s < Sn; s += 64) cnt += (text[b*Sn + s] != 0) ? 1 : 0;
  for (int off = 32; off; off >>= 1) cnt += __shfl_down(cnt, off);
  if (lane == 0){ lens_i[b] = cnt; out_lens[b] = (float)cnt; }
}

// ---------------------------------------------------------------------------
// Persistent bidirectional LSTM, 2 blocks per (bg,d) group (col halves).
// grid = (2 cg, 4 bg, 2 d) = 16 blocks, 256 threads, 1 wave/SIMD (512 VGPR).
// Weights register/AGPR-stationary: 8 col-tiles x 12 k-tiles of v8s per wave.
// Cross-block: RELAXED agent atomics only (no buffer_inv / buffer_wbl2);
// ordering by explicit s_waitcnt vmcnt(0) + relaxed flag; double-buffered.
// ---------------------------------------------------------------------------
__global__ __launch_bounds__(256, 1) void k_lstm(
    const int* __restrict__ text, const float* __restrict__ emb,
    const unsigned short* __restrict__ UW, const float* __restrict__ bpk,
    unsigned short* __restrict__ h_hist, int* __restrict__ flags,
    u64t* __restrict__ hbuf)
{
  __shared__ unsigned short A_s[16][392];  // [m][k]: 0..255 h, 256..383 x, pad
  __shared__ float z_s[16*520];            // swizzled [row][col-half 512]
  __shared__ float bias_s[512];            // swizzled, local col
  __shared__ int   tok_s[16][Sn];          // this group's tokens

  int cg = blockIdx.x, bg = blockIdx.y, d = blockIdx.z;
  int tid = threadIdx.x;
  int wv = tid >> 6, lane = tid & 63, q = lane >> 4, r = lane & 15;
  int group = d*4 + bg;
  int m  = tid >> 4, i16 = tid & 15;

  int* myflag = flags + group*2 + cg;
  int* pflag  = flags + group*2 + (cg^1);
  u64t* pub_base = hbuf + (size_t)((group*2 + cg)*2)*512;        // my slots
  const u64t* sub_base = hbuf + (size_t)((group*2 + (cg^1))*2)*512; // partner

  // ---- weight fragments: 8 col-tiles x 12 k-tiles (register/AGPR resident) ----
  v8s wf[8][12];
  #pragma unroll
  for (int ct = 0; ct < 8; ++ct){
    const unsigned short* base =
        UW + ((size_t)(d*NG + cg*512 + wv*128 + ct*16 + r))*NK;
    #pragma unroll
    for (int kt = 0; kt < 12; ++kt)
      wf[ct][kt] = *(const v8s*)(base + kt*32 + q*8);
  }
  // ---- bias (swizzled) + tokens into LDS ----
  for (int lc = tid; lc < 512; lc += 256){
    int p = lc ^ (((lc >> 5) & 7) << 2);
    bias_s[p] = bpk[d*NG + cg*512 + lc];
  }
  for (int idx = tid; idx < 16*Sn; idx += 256){
    int mm = idx >> 9, s = idx & 511;
    tok_s[mm][s] = text[(bg*16 + mm)*Sn + s];
  }
  __syncthreads();

  float c_[8];
  #pragma unroll
  for (int j = 0; j < 8; ++j) c_[j] = 0.f;

  for (int t = 0; t < Sn; ++t){
    int t_act = d ? (Sn - 1 - t) : t;

    if (t > 0){
      asm volatile("s_waitcnt vmcnt(0)" ::: "memory");   // drain h publishes
      __syncthreads();                                   // all waves drained
      if (tid == 0)
        __hip_atomic_store(myflag, t, __ATOMIC_RELAXED, __HIP_MEMORY_SCOPE_AGENT);
    }

    // x loads (emb row slice for batch m)
    int tok = tok_s[m][t_act];
    float4 x0 = *(const float4*)(emb + (size_t)tok*EMBn + i16*8);
    float4 x1 = *(const float4*)(emb + (size_t)tok*EMBn + i16*8 + 4);

    if (t > 0 && tid == 0){
      while (__hip_atomic_load(pflag, __ATOMIC_RELAXED,
                               __HIP_MEMORY_SCOPE_AGENT) < t)
        __builtin_amdgcn_s_sleep(2);
    }

    // stage x -> A_s
    {
      ushort4 lo = { f2bf(x0.x), f2bf(x0.y), f2bf(x0.z), f2bf(x0.w) };
      ushort4 hi = { f2bf(x1.x), f2bf(x1.y), f2bf(x1.z), f2bf(x1.w) };
      *(ushort4*)&A_s[m][HIDn + i16*8]     = lo;
      *(ushort4*)&A_s[m][HIDn + i16*8 + 4] = hi;
    }
    __syncthreads();   // B1: poll visible to all

    if (t > 0){
      int slot = (t - 1) & 1;
      const u64t* src = sub_base + (size_t)slot*512 + m*32 + i16*2;
      u64t a = __hip_atomic_load(src,     __ATOMIC_RELAXED, __HIP_MEMORY_SCOPE_AGENT);
      u64t b = __hip_atomic_load(src + 1, __ATOMIC_RELAXED, __HIP_MEMORY_SCOPE_AGENT);
      *(u64t*)&A_s[m][(cg^1)*128 + i16*8]     = a;
      *(u64t*)&A_s[m][(cg^1)*128 + i16*8 + 4] = b;
    }
    __syncthreads();   // B2: A_s complete

    // ---- MFMA: z[16][512-half] ----
    v4f acc[8];
    #pragma unroll
    for (int ct = 0; ct < 8; ++ct) acc[ct] = (v4f){0.f,0.f,0.f,0.f};
    if (t == 0){
      #pragma unroll
      for (int kt = 8; kt < 12; ++kt){
        v8s a = *(const v8s*)&A_s[r][kt*32 + q*8];
        #pragma unroll
        for (int ct = 0; ct < 8; ++ct)
          acc[ct] = __builtin_amdgcn_mfma_f32_16x16x32_bf16(a, wf[ct][kt], acc[ct], 0, 0, 0);
      }
    } else {
      #pragma unroll
      for (int kt = 0; kt < 12; ++kt){
        v8s a = *(const v8s*)&A_s[r][kt*32 + q*8];
        #pragma unroll
        for (int ct = 0; ct < 8; ++ct)
          acc[ct] = __builtin_amdgcn_mfma_f32_16x16x32_bf16(a, wf[ct][kt], acc[ct], 0, 0, 0);
      }
    }
    // z -> LDS (bank-swizzled)
    #pragma unroll
    for (int ct = 0; ct < 8; ++ct){
      int col = wv*128 + ct*16 + r;
      int p = col ^ (((col >> 5) & 7) << 2);
      #pragma unroll
      for (int i = 0; i < 4; ++i)
        z_s[(q*4 + i)*520 + p] = acc[ct][i];
    }
    __syncthreads();   // B3

    // ---- gates: thread -> (m, 8 contiguous local units i16*8..+8) ----
    unsigned short hsh[8];
    #pragma unroll
    for (int j = 0; j < 8; ++j){
      int lc = i16*32 + j*4;
      int p = lc ^ (((lc >> 5) & 7) << 2);
      float4 z4 = *(const float4*)&z_s[m*520 + p];
      float4 b4 = *(const float4*)&bias_s[p];
      float ii = sigm(z4.x + b4.x);
      float ff = sigm(z4.y + b4.y);
      float gg = tanh_(z4.z + b4.z);
      float oo = sigm(z4.w + b4.w);
      c_[j] = ff*c_[j] + ii*gg;
      float h = oo*tanh_(c_[j]);
      hsh[j] = f2bf(h);
    }
    // own h -> A_s (for next step's MFMA)
    {
      ushort4 v0 = { hsh[0], hsh[1], hsh[2], hsh[3] };
      ushort4 v1 = { hsh[4], hsh[5], hsh[6], hsh[7] };
      *(ushort4*)&A_s[m][cg*128 + i16*8]     = v0;
      *(ushort4*)&A_s[m][cg*128 + i16*8 + 4] = v1;
    }
    // h -> h_hist (normal store; dispatch-boundary flush covers k_logits)
    {
      uint4 hv;
      hv.x = (unsigned)hsh[0] | ((unsigned)hsh[1] << 16);
      hv.y = (unsigned)hsh[2] | ((unsigned)hsh[3] << 16);
      hv.z = (unsigned)hsh[4] | ((unsigned)hsh[5] << 16);
      hv.w = (unsigned)hsh[6] | ((unsigned)hsh[7] << 16);
      *(uint4*)(h_hist + ((size_t)(d*Sn + t_act)*Bn + bg*16 + m)*HIDn
                + cg*128 + i16*8) = hv;
      // publish to partner (relaxed agent atomics, double-buffered)
      u64t pa = ((u64t)hv.y << 32) | hv.x;
      u64t pb = ((u64t)hv.w << 32) | hv.z;
      u64t* dst = pub_base + (size_t)(t & 1)*512 + m*32 + i16*2;
      __hip_atomic_store(dst,     pa, __ATOMIC_RELAXED, __HIP_MEMORY_SCOPE_AGENT);
      __hip_atomic_store(dst + 1, pb, __ATOMIC_RELAXED, __HIP_MEMORY_SCOPE_AGENT);
    }
  }
}

// ---------------------------------------------------------------------------
// logits[b][s][tag] = concat(hf,hb) @ W_d + b_d.
// ---------------------------------------------------------------------------
__global__ __launch_bounds__(256) void k_logits(
    const unsigned short* __restrict__ h_hist, const float* __restrict__ Wd,
    const float* __restrict__ bd, float* __restrict__ out)
{
  __shared__ float Wd_s[2*HIDn*NTAG];
  __shared__ float bd_s[NTAG];
  for (int i = threadIdx.x; i < 2*HIDn*NTAG; i += 256) Wd_s[i] = Wd[i];
  if (threadIdx.x < NTAG) bd_s[threadIdx.x] = bd[threadIdx.x];
  __syncthreads();

  int n = blockIdx.x*256 + threadIdx.x;   // n = b*512 + s
  int b = n >> 9, s = n & 511;
  float acc[NTAG];
  #pragma unroll
  for (int k = 0; k < NTAG; ++k) acc[k] = bd_s[k];

  const uint4* hf = (const uint4*)(h_hist + ((size_t)s*Bn + b)*HIDn);
  const uint4* hb = (const uint4*)(h_hist + ((size_t)(Sn + s)*Bn + b)*HIDn);
  #pragma unroll 4
  for (int ch = 0; ch < HIDn/8; ++ch){
    uint4 vf = hf[ch], vb = hb[ch];
    unsigned int wsv[8] = {vf.x, vf.y, vf.z, vf.w, vb.x, vb.y, vb.z, vb.w};
    #pragma unroll
    for (int half = 0; half < 2; ++half){
      int jbase = half*HIDn + ch*8;
      #pragma unroll
      for (int e = 0; e < 4; ++e){
        unsigned int u = wsv[half*4 + e];
        float hlo = bf2f((unsigned short)(u & 0xFFFF));
        float hhi = bf2f((unsigned short)(u >> 16));
        const float* w0 = &Wd_s[(jbase + e*2    )*NTAG];
        const float* w1 = &Wd_s[(jbase + e*2 + 1)*NTAG];
        #pragma unroll
        for (int k = 0; k < NTAG; ++k) acc[k] += hlo*w0[k] + hhi*w1[k];
      }
    }
  }
  float* o = out + (size_t)n*NTAG;
  #pragma unroll
  for (int k = 0; k < NTAG; ++k) o[k] = acc[k];
}

// ---------------------------------------------------------------------------
__global__ __launch_bounds__(64) void k_crf(
    const float* __restrict__ logits, const int* __restrict__ labels,
    const float* __restrict__ trans, const int* __restrict__ lens_i,
    float* __restrict__ out_ll)
{
  int b = blockIdx.x, lane = threadIdx.x;
  int len = lens_i[b];
  const float* lg = logits + (size_t)b*Sn*NTAG;
  const int* lab = labels + b*Sn;

  float sc = 0.f;
  for (int s = lane; s < Sn; s += 64){
    if (s < len)     sc += lg[s*NTAG + lab[s]];
    if (s < len - 1) sc += trans[lab[s]*NTAG + lab[s+1]];
  }
  for (int off = 32; off; off >>= 1) sc += __shfl_down(sc, off);
  sc = __shfl(sc, 0);

  int j = (lane < NTAG) ? lane : (NTAG - 1);
  float Tj[NTAG];
  #pragma unroll
  for (int i = 0; i < NTAG; ++i) Tj[i] = trans[i*NTAG + j];
  float alpha = lg[j];
  float nxt = lg[NTAG + j];
  for (int t = 1; t < Sn; ++t){
    float cur = nxt;
    if (t < Sn - 1) nxt = lg[(t+1)*NTAG + j];
    float v[NTAG]; float mx;
    v[0] = __shfl(alpha, 0) + Tj[0]; mx = v[0];
    #pragma unroll
    for (int i = 1; i < NTAG; ++i){ v[i] = __shfl(alpha, i) + Tj[i]; mx = fmaxf(mx, v[i]); }
    float ssum = 0.f;
    #pragma unroll
    for (int i = 0; i < NTAG; ++i) ssum += __expf(v[i] - mx);
    float na = mx + __logf(ssum) + cur;
    if (t < len) alpha = na;
  }
  float m2 = __shfl(alpha, 0);
  #pragma unroll
  for (int i = 1; i < NTAG; ++i) m2 = fmaxf(m2, __shfl(alpha, i));
  float s2 = 0.f;
  #pragma unroll
  for (int i = 0; i < NTAG; ++i) s2 += __expf(__shfl(alpha, i) - m2);
  float ln = m2 + __logf(s2);
  if (lane == 0) out_ll[b] = sc - ln;
}

// ---------------------------------------------------------------------------
extern "C" void kernel_launch(void* const* d_in, const int* in_sizes, int n_in,
                              void* d_out, int out_size, void* d_ws, size_t ws_size,
                              hipStream_t stream)
{
  const int*   text   = (const int*)  d_in[0];
  const int*   labels = (const int*)  d_in[1];
  const float* emb    = (const float*)d_in[2];
  const float* W_f    = (const float*)d_in[3];
  const float* U_f    = (const float*)d_in[4];
  const float* b_f    = (const float*)d_in[5];
  const float* W_b    = (const float*)d_in[6];
  const float* U_b    = (const float*)d_in[7];
  const float* b_b    = (const float*)d_in[8];
  const float* W_d    = (const float*)d_in[9];
  const float* b_d    = (const float*)d_in[10];
  const float* trans  = (const float*)d_in[11];
  float* out = (float*)d_out;                  // [logits 294912][lens 64][ll 64]

  char* w = (char*)d_ws;
  int*            lens_i = (int*)w;                            // 0      (256 B)
  int*            flags  = (int*)(w + 256);                    // 256    (16 ints)
  float*          bpk    = (float*)(w + 512);                  // 512    (8 KiB)
  u64t*           hbuf   = (u64t*)(w + 8704);                  // 8704   (128 KiB)
  unsigned short* UW     = (unsigned short*)(w + 139776);      // 139776 (1.5 MiB)
  unsigned short* h_hist = (unsigned short*)(w + 1712640);     // 32 MiB

  hipLaunchKernelGGL(k_zero, dim3(1), dim3(64), 0, stream, flags, 16);
  hipLaunchKernelGGL(k_conv, dim3(NG, 2), dim3(128), 0, stream,
                     W_f, U_f, b_f, W_b, U_b, b_b, UW, bpk);
  hipLaunchKernelGGL(k_lens, dim3(Bn), dim3(64), 0, stream,
                     text, out + Bn*Sn*NTAG, lens_i);

  void* args[] = { (void*)&text, (void*)&emb, (void*)&UW, (void*)&bpk,
                   (void*)&h_hist, (void*)&flags, (void*)&hbuf };
  hipLaunchCooperativeKernel((const void*)k_lstm, dim3(2, 4, 2), dim3(256),
                             args, 0, stream);

  hipLaunchKernelGGL(k_logits, dim3(Bn*Sn/256), dim3(256), 0, stream,
                     h_hist, W_d, b_d, out);
  hipLaunchKernelGGL(k_crf, dim3(Bn), dim3(64), 0, stream,
                     out, labels, trans, lens_i, out + Bn*Sn*NTAG + Bn);
}